// Round 2
// baseline (12326.616 us; speedup 1.0000x reference)
//
#include <hip/hip_runtime.h>

typedef __attribute__((ext_vector_type(8))) short short8;
typedef __attribute__((ext_vector_type(4))) float f32x4;
typedef __attribute__((ext_vector_type(2))) float f32x2;
typedef __attribute__((ext_vector_type(4))) unsigned short us4;
typedef __attribute__((ext_vector_type(2))) unsigned short us2;

#define N_NODES 4096
#define T_STEPS 128
#define H_DIM   64
#define NBLK    256
#define NTHR    512      // 8 waves
#define ROWS    16       // graph rows per block

// workspace layout (bytes)
#define WS_FLAGS 0u          // 256 flags, 128B apart = 32 KB
#define WS_WT    32768u      // Wt[256][96] bf16 = 48 KB  (combined [Wih;Whh] transposed)
#define WS_WQT   81920u      // Wqt[64][64] bf16 = 8 KB
#define WS_Q0    98304u      // qT[64][4096] bf16 = 512 KB
#define WS_Q1    622592u     // second q buffer
#define WS_NEED  1146880u

__device__ __forceinline__ unsigned short f2bf(float f) {   // RNE fp32->bf16
    unsigned x = __float_as_uint(f);
    unsigned r = ((x >> 16) & 1u) + 0x7fffu;
    return (unsigned short)((x + r) >> 16);
}
// 8 consecutive fp32 -> short8 bf16 by truncation (v_perm_b32, 1 inst / pair)
__device__ __forceinline__ short8 cvt8_trunc(const float* p) {
    f32x4 a = *(const f32x4*)p;
    f32x4 b = *(const f32x4*)(p + 4);
    union { unsigned u[4]; short8 s; } cv;
    cv.u[0] = __builtin_amdgcn_perm(__float_as_uint(a[1]), __float_as_uint(a[0]), 0x07060302u);
    cv.u[1] = __builtin_amdgcn_perm(__float_as_uint(a[3]), __float_as_uint(a[2]), 0x07060302u);
    cv.u[2] = __builtin_amdgcn_perm(__float_as_uint(b[1]), __float_as_uint(b[0]), 0x07060302u);
    cv.u[3] = __builtin_amdgcn_perm(__float_as_uint(b[3]), __float_as_uint(b[2]), 0x07060302u);
    return cv.s;
}
__device__ __forceinline__ float fast_sigmoid(float x) { return 1.f / (1.f + __expf(-x)); }
__device__ __forceinline__ float fast_tanh(float x)    { return 1.f - 2.f / (1.f + __expf(2.f * x)); }

// 256 blocks on 256 CUs, <=1 block/CU resources => all resident => flag barrier safe.
// ws poisoned 0xAA => flags start negative; epochs 1,2,... count up.
__device__ __forceinline__ void grid_barrier(int* flags, int bid, int tid, int epoch) {
    __syncthreads();
    __threadfence();                                   // release
    if (tid == 0)
        __hip_atomic_store(&flags[bid * 32], epoch, __ATOMIC_RELEASE, __HIP_MEMORY_SCOPE_AGENT);
    if (tid < NBLK) {
        int guard = 0;
        while (__hip_atomic_load(&flags[tid * 32], __ATOMIC_RELAXED, __HIP_MEMORY_SCOPE_AGENT) < epoch) {
            if (++guard > (1 << 22)) break;            // safety valve
        }
    }
    __syncthreads();
    __threadfence();                                   // acquire
}

#define MFMA16(a, b, c) __builtin_amdgcn_mfma_f32_16x16x32_bf16((a), (b), (c), 0, 0, 0)

__global__ __launch_bounds__(NTHR, 1) void glstm_kernel(
    const float* __restrict__ x,      // [4096][128][32] f32
    const float* __restrict__ adj,    // [4096][4096] f32
    const float* __restrict__ w_ih,   // [32][256] f32
    const float* __restrict__ w_hh,   // [64][256] f32
    const float* __restrict__ bias,   // [256] f32
    const float* __restrict__ w_q,    // [64][64] f32
    const float* __restrict__ bias_q, // [64] f32
    float* __restrict__ out,          // [4096][128][64] f32
    unsigned char* __restrict__ ws)
{
    const int tid  = threadIdx.x;
    const int bid  = blockIdx.x;
    const int wave = tid >> 6;       // 0..7
    const int lane = tid & 63;
    const int l15  = lane & 15;
    const int quad = lane >> 4;      // 0..3
    const int rowbase = bid * ROWS;

    int* flags = (int*)(ws + WS_FLAGS);
    unsigned short* Wt  = (unsigned short*)(ws + WS_WT);
    unsigned short* Wqt = (unsigned short*)(ws + WS_WQT);
    unsigned short* qb0 = (unsigned short*)(ws + WS_Q0);
    unsigned short* qb1 = (unsigned short*)(ws + WS_Q1);

    __shared__ float gate_lds[4][16][64];   // post-activation gates, 16 KB
    __shared__ float sPart[8][16][64];      // per-wave K-partials of adj@q, 32 KB
    __shared__ float c_lds[16][64];         // cell state f32, 4 KB
    __shared__ unsigned short h_lds[16][72];// h bf16, padded stride

    // ---------------- init: weight transposes (fp32->bf16) + q0 + zero state ----------------
    if (tid < 96) {
        float v = (tid < 32) ? w_ih[tid * 256 + bid] : w_hh[(tid - 32) * 256 + bid];
        Wt[bid * 96 + tid] = f2bf(v);
    }
    if (bid < 64 && tid < 64) Wqt[bid * 64 + tid] = f2bf(w_q[tid * 64 + bid]);
    for (int idx = tid; idx < ROWS * 64; idx += NTHR) {   // q0 = tanh(bq) broadcast
        int r = idx >> 6, hh = idx & 63;
        qb0[hh * N_NODES + rowbase + r] = f2bf(fast_tanh(bias_q[hh]));
    }
    for (int idx = tid; idx < ROWS * 64; idx += NTHR) {
        int r = idx >> 6, cc = idx & 63;
        c_lds[r][cc] = 0.f;
        h_lds[r][cc] = 0;
    }
    grid_barrier(flags, bid, tid, 1);

    const float* xlane   = x   + (size_t)(rowbase + l15) * T_STEPS * 32 + quad * 8;
    const float* adjlane = adj + (size_t)(rowbase + l15) * N_NODES + wave * 512 + quad * 8;

    for (int t = 0; t < T_STEPS; ++t) {
        const unsigned short* qcur = (t & 1) ? qb1 : qb0;
        unsigned short*       qnxt = (t & 1) ? qb0 : qb1;

        // ---------------- Phase A: gates = [x_t | h] @ W + b ----------------
        {
            const int g    = wave >> 1;   // gate 0..3 (i,f,g,o)
            const int half = wave & 1;    // 32-col half within gate
            f32x4 acc0 = {0.f, 0.f, 0.f, 0.f};
            f32x4 acc1 = {0.f, 0.f, 0.f, 0.f};
            const int nc0 = g * 64 + half * 32 + l15;
            short8 a0 = cvt8_trunc(xlane + t * 32);          // k 0..31 from x_t
            acc0 = MFMA16(a0, *(const short8*)(Wt + (nc0)      * 96 + quad * 8), acc0);
            acc1 = MFMA16(a0, *(const short8*)(Wt + (nc0 + 16) * 96 + quad * 8), acc1);
#pragma unroll
            for (int kk = 1; kk < 3; ++kk) {                 // k 32..95 from h
                short8 a = *(const short8*)(&h_lds[l15][(kk - 1) * 32 + quad * 8]);
                acc0 = MFMA16(a, *(const short8*)(Wt + (nc0)      * 96 + kk * 32 + quad * 8), acc0);
                acc1 = MFMA16(a, *(const short8*)(Wt + (nc0 + 16) * 96 + kk * 32 + quad * 8), acc1);
            }
#pragma unroll
            for (int nt = 0; nt < 2; ++nt) {
                f32x4 acc = nt ? acc1 : acc0;
                int ncol = nc0 + nt * 16;
                float bv = bias[ncol];
                int colg = half * 32 + nt * 16 + l15;
#pragma unroll
                for (int r = 0; r < 4; ++r) {
                    float v = acc[r] + bv;
                    v = (g == 2) ? fast_tanh(v) : fast_sigmoid(v);
                    gate_lds[g][quad * 4 + r][colg] = v;
                }
            }
        }

        // ---------------- Phase B: s = adj[rows,:] @ q_t  (waves split K) ----------------
        {
            f32x4 acc[4];
#pragma unroll
            for (int nt = 0; nt < 4; ++nt) acc[nt] = (f32x4){0.f, 0.f, 0.f, 0.f};
            const float* ap = adjlane;
            const int koff  = wave * 512 + quad * 8;
            const unsigned short* qp0 = qcur + (0 * 16 + l15) * N_NODES + koff;
            const unsigned short* qp1 = qcur + (1 * 16 + l15) * N_NODES + koff;
            const unsigned short* qp2 = qcur + (2 * 16 + l15) * N_NODES + koff;
            const unsigned short* qp3 = qcur + (3 * 16 + l15) * N_NODES + koff;
#pragma unroll 4
            for (int kk = 0; kk < 16; ++kk) {
                short8 a  = cvt8_trunc(ap);
                short8 b0 = *(const short8*)qp0;
                short8 b1 = *(const short8*)qp1;
                short8 b2 = *(const short8*)qp2;
                short8 b3 = *(const short8*)qp3;
                ap += 32; qp0 += 32; qp1 += 32; qp2 += 32; qp3 += 32;
                acc[0] = MFMA16(a, b0, acc[0]);
                acc[1] = MFMA16(a, b1, acc[1]);
                acc[2] = MFMA16(a, b2, acc[2]);
                acc[3] = MFMA16(a, b3, acc[3]);
            }
#pragma unroll
            for (int nt = 0; nt < 4; ++nt)
#pragma unroll
                for (int r = 0; r < 4; ++r)
                    sPart[wave][quad * 4 + r][nt * 16 + l15] = acc[nt][r];
        }
        __syncthreads();

        // ---------------- Phase C: state update + h output (fp32) ----------------
        {
            const int r  = tid >> 5;            // 0..15
            const int c0 = (tid & 31) * 2;      // 2 consecutive cols
            float hn[2];
#pragma unroll
            for (int j = 0; j < 2; ++j) {
                int cc = c0 + j;
                float s = 0.f;
#pragma unroll
                for (int w8 = 0; w8 < 8; ++w8) s += sPart[w8][r][cc];
                float iv = gate_lds[0][r][cc];
                float fv = gate_lds[1][r][cc];
                float gv = gate_lds[2][r][cc];
                float ov = gate_lds[3][r][cc];
                float cn = fv * (c_lds[r][cc] + s) + iv * gv;
                hn[j] = ov * fast_tanh(cn);
                c_lds[r][cc] = cn;
            }
            us2 hv; hv[0] = f2bf(hn[0]); hv[1] = f2bf(hn[1]);
            *(us2*)(&h_lds[r][c0]) = hv;
            *(f32x2*)(out + ((size_t)(rowbase + r) * T_STEPS + t) * H_DIM + c0) = (f32x2){hn[0], hn[1]};
        }
        __syncthreads();

        // ---------------- Phase D: q_{t+1} = tanh(h_t @ Wq + bq), stored transposed ----------------
        if (t < T_STEPS - 1 && wave < 4) {
            f32x4 acc = {0.f, 0.f, 0.f, 0.f};
            const int hh = wave * 16 + l15;
#pragma unroll
            for (int kk = 0; kk < 2; ++kk) {
                short8 a = *(const short8*)(&h_lds[l15][kk * 32 + quad * 8]);
                short8 b = *(const short8*)(Wqt + hh * 64 + kk * 32 + quad * 8);
                acc = MFMA16(a, b, acc);
            }
            float bqv = bias_q[hh];
            us4 qv;
#pragma unroll
            for (int r = 0; r < 4; ++r) qv[r] = f2bf(fast_tanh(acc[r] + bqv));
            *(us4*)(qnxt + hh * N_NODES + rowbase + quad * 4) = qv;
        }

        if (t < T_STEPS - 1) grid_barrier(flags, bid, tid, t + 2);
    }
}

extern "C" void kernel_launch(void* const* d_in, const int* in_sizes, int n_in,
                              void* d_out, int out_size, void* d_ws, size_t ws_size,
                              hipStream_t stream) {
    if (ws_size < WS_NEED) return;
    const float* x      = (const float*)d_in[0];
    const float* adj    = (const float*)d_in[1];
    const float* w_ih   = (const float*)d_in[2];
    const float* w_hh   = (const float*)d_in[3];
    const float* bias   = (const float*)d_in[4];
    const float* w_q    = (const float*)d_in[5];
    const float* bias_q = (const float*)d_in[6];
    glstm_kernel<<<NBLK, NTHR, 0, stream>>>(x, adj, w_ih, w_hh, bias, w_q, bias_q,
                                            (float*)d_out, (unsigned char*)d_ws);
}

// Round 3
// 4825.297 us; speedup vs baseline: 2.5546x; 2.5546x over previous
//
#include <hip/hip_runtime.h>

typedef __attribute__((ext_vector_type(8))) short short8;
typedef __attribute__((ext_vector_type(4))) float f32x4;
typedef __attribute__((ext_vector_type(2))) float f32x2;
typedef __attribute__((ext_vector_type(4))) unsigned short us4;
typedef __attribute__((ext_vector_type(2))) unsigned short us2;

#define N_NODES 4096
#define T_STEPS 128
#define H_DIM   64
#define NBLK    256
#define NTHR    512      // 8 waves
#define ROWS    16       // graph rows per block

// workspace layout (bytes)
#define WS_FLAGS 0u          // 256 flags, 128B apart = 32 KB
#define WS_WT    32768u      // Wt[256][96] bf16 (combined [Wih;Whh] transposed)
#define WS_WQT   81920u      // Wqt[64][64] bf16
#define WS_Q0    98304u      // qT[64][4096] bf16 = 512 KB
#define WS_Q1    622592u
#define WS_NEED  1146880u

// dynamic LDS layout
#define ADJ_STRIDE 4104                  // 4096 + 8 pad (row stride == 4 banks -> ~baseline b128)
#define ADJ_BYTES  (16u * ADJ_STRIDE * 2u)          // 131328
#define GATE_BYTES 16384u                // [4][16][64] f32
#define S_BYTES    4224u                 // [16][66] f32 (padded for ds_add)
#define C_BYTES    4096u                 // [16][64] f32
#define H_BYTES    2304u                 // [16][72] bf16
#define SMEM_SMALL (GATE_BYTES + S_BYTES + C_BYTES + H_BYTES)            // 27008
#define SMEM_BIG   (ADJ_BYTES + SMEM_SMALL)                              // 158336

__device__ __forceinline__ unsigned short f2bf(float f) {   // RNE fp32->bf16
    unsigned x = __float_as_uint(f);
    unsigned r = ((x >> 16) & 1u) + 0x7fffu;
    return (unsigned short)((x + r) >> 16);
}
__device__ __forceinline__ short8 cvt8_trunc_v(f32x4 a, f32x4 b) {  // truncating pack
    union { unsigned u[4]; short8 s; } cv;
    cv.u[0] = __builtin_amdgcn_perm(__float_as_uint(a[1]), __float_as_uint(a[0]), 0x07060302u);
    cv.u[1] = __builtin_amdgcn_perm(__float_as_uint(a[3]), __float_as_uint(a[2]), 0x07060302u);
    cv.u[2] = __builtin_amdgcn_perm(__float_as_uint(b[1]), __float_as_uint(b[0]), 0x07060302u);
    cv.u[3] = __builtin_amdgcn_perm(__float_as_uint(b[3]), __float_as_uint(b[2]), 0x07060302u);
    return cv.s;
}
__device__ __forceinline__ short8 cvt8_trunc(const float* p) {
    return cvt8_trunc_v(*(const f32x4*)p, *(const f32x4*)(p + 4));
}
__device__ __forceinline__ float fast_sigmoid(float x) { return 1.f / (1.f + __expf(-x)); }
__device__ __forceinline__ float fast_tanh(float x)    { return 1.f - 2.f / (1.f + __expf(2.f * x)); }

// 256 blocks on 256 CUs (1 block/CU) => all resident => flag barrier safe.
// ws poisoned 0xAA => flags start negative; epochs count 1,2,...
// Cache maintenance (wbl2/inv) executed by ONE wave per block, not all eight.
__device__ __forceinline__ void grid_barrier(int* flags, int bid, int tid, int epoch) {
    __syncthreads();                                     // all waves' stores drained (vmcnt 0)
    if (tid == 0) {
        __builtin_amdgcn_fence(__ATOMIC_RELEASE, "agent");   // wbl2: publish q/out to LLC
        __hip_atomic_store(&flags[bid * 32], epoch, __ATOMIC_RELAXED, __HIP_MEMORY_SCOPE_AGENT);
    }
    if (tid < NBLK) {
        int guard = 0;
        while (__hip_atomic_load(&flags[tid * 32], __ATOMIC_RELAXED, __HIP_MEMORY_SCOPE_AGENT) < epoch) {
            __builtin_amdgcn_s_sleep(32);                // ~2k cyc backoff: cut poll storms
            if (++guard > (1 << 17)) break;              // safety valve
        }
    }
    __syncthreads();
    if (tid == 0) __builtin_amdgcn_fence(__ATOMIC_ACQUIRE, "agent");  // inv stale L1/L2
    __syncthreads();
}

#define MFMA16(a, b, c) __builtin_amdgcn_mfma_f32_16x16x32_bf16((a), (b), (c), 0, 0, 0)

template <bool ADJL>
__global__ __launch_bounds__(NTHR, 1) void glstm_kernel(
    const float* __restrict__ x,      // [4096][128][32]
    const float* __restrict__ adj,    // [4096][4096]
    const float* __restrict__ w_ih,   // [32][256]
    const float* __restrict__ w_hh,   // [64][256]
    const float* __restrict__ bias,   // [256]
    const float* __restrict__ w_q,    // [64][64]
    const float* __restrict__ bias_q, // [64]
    float* __restrict__ out,          // [4096][128][64]
    unsigned char* __restrict__ ws)
{
    const int tid  = threadIdx.x;
    const int bid  = blockIdx.x;
    const int wave = tid >> 6;
    const int lane = tid & 63;
    const int l15  = lane & 15;
    const int quad = lane >> 4;
    const int rowbase = bid * ROWS;

    int* flags = (int*)(ws + WS_FLAGS);
    unsigned short* Wt  = (unsigned short*)(ws + WS_WT);
    unsigned short* Wqt = (unsigned short*)(ws + WS_WQT);
    unsigned short* qb0 = (unsigned short*)(ws + WS_Q0);
    unsigned short* qb1 = (unsigned short*)(ws + WS_Q1);

    extern __shared__ unsigned char smem[];
    unsigned short* adj_lds = (unsigned short*)smem;                 // [16][4104] (ADJL only)
    const unsigned off = ADJL ? ADJ_BYTES : 0u;
    float* gate_lds = (float*)(smem + off);                          // [4][16][64]
    float* s_lds    = (float*)(smem + off + GATE_BYTES);             // [16][66]
    float* c_lds    = (float*)(smem + off + GATE_BYTES + S_BYTES);   // [16][64]
    unsigned short* h_lds = (unsigned short*)(smem + off + GATE_BYTES + S_BYTES + C_BYTES); // [16][72]

    // ---------------- init: weight staging, q0, zero state, adj->LDS ----------------
    if (tid < 96) {
        float v = (tid < 32) ? w_ih[tid * 256 + bid] : w_hh[(tid - 32) * 256 + bid];
        Wt[bid * 96 + tid] = f2bf(v);
    }
    if (bid < 64 && tid < 64) Wqt[bid * 64 + tid] = f2bf(w_q[tid * 64 + bid]);
    for (int idx = tid; idx < ROWS * 64; idx += NTHR) {      // q0 = tanh(bq)
        int r = idx >> 6, hh = idx & 63;
        qb0[hh * N_NODES + rowbase + r] = f2bf(fast_tanh(bias_q[hh]));
    }
    for (int idx = tid; idx < ROWS * 64; idx += NTHR) {
        int r = idx >> 6, cc = idx & 63;
        c_lds[r * 64 + cc] = 0.f;
        s_lds[r * 66 + cc] = 0.f;
        h_lds[r * 72 + cc] = 0;
    }
    if (ADJL) {
        for (int idx = tid; idx < ROWS * N_NODES; idx += NTHR) {
            int r = idx >> 12, c = idx & (N_NODES - 1);
            adj_lds[r * ADJ_STRIDE + c] = f2bf(adj[(size_t)(rowbase + r) * N_NODES + c]);
        }
    }
    grid_barrier(flags, bid, tid, 1);

    // ---------------- hoist weight fragments into registers (reused all 128 steps) ----------------
    const int g    = wave >> 1;        // gate 0..3
    const int half = wave & 1;
    const int nc0  = g * 64 + half * 32 + l15;
    short8 wA[2][3];
#pragma unroll
    for (int nt = 0; nt < 2; ++nt)
#pragma unroll
        for (int kk = 0; kk < 3; ++kk)
            wA[nt][kk] = *(const short8*)(Wt + (nc0 + nt * 16) * 96 + kk * 32 + quad * 8);
    const float bv0 = bias[nc0], bv1 = bias[nc0 + 16];
    const int hhq = (wave & 3) * 16 + l15;
    short8 wQ[2];
#pragma unroll
    for (int kk = 0; kk < 2; ++kk)
        wQ[kk] = *(const short8*)(Wqt + hhq * 64 + kk * 32 + quad * 8);
    const float bqv = bias_q[hhq];

    const float* xlane   = x + (size_t)(rowbase + l15) * T_STEPS * 32 + quad * 8;
    const float* adjlane = adj + (size_t)(rowbase + l15) * N_NODES + wave * 512 + quad * 8;
    const unsigned short* albase = adj_lds + l15 * ADJ_STRIDE + wave * 512 + quad * 8;

    f32x4 xa = *(const f32x4*)(xlane);          // prefetched x_t fragment
    f32x4 xb = *(const f32x4*)(xlane + 4);

    for (int t = 0; t < T_STEPS; ++t) {
        const unsigned short* qcur = (t & 1) ? qb1 : qb0;
        unsigned short*       qnxt = (t & 1) ? qb0 : qb1;

        // ---------------- Phase A: gates = [x_t | h] @ W + b ----------------
        {
            f32x4 acc0 = {0.f, 0.f, 0.f, 0.f};
            f32x4 acc1 = {0.f, 0.f, 0.f, 0.f};
            short8 a0 = cvt8_trunc_v(xa, xb);
            acc0 = MFMA16(a0, wA[0][0], acc0);
            acc1 = MFMA16(a0, wA[1][0], acc1);
#pragma unroll
            for (int kk = 1; kk < 3; ++kk) {
                short8 a = *(const short8*)(h_lds + l15 * 72 + (kk - 1) * 32 + quad * 8);
                acc0 = MFMA16(a, wA[0][kk], acc0);
                acc1 = MFMA16(a, wA[1][kk], acc1);
            }
#pragma unroll
            for (int nt = 0; nt < 2; ++nt) {
                f32x4 acc = nt ? acc1 : acc0;
                float bv  = nt ? bv1 : bv0;
                int colg  = half * 32 + nt * 16 + l15;
#pragma unroll
                for (int r = 0; r < 4; ++r) {
                    float v = acc[r] + bv;
                    v = (g == 2) ? fast_tanh(v) : fast_sigmoid(v);
                    gate_lds[(g * 16 + quad * 4 + r) * 64 + colg] = v;
                }
            }
        }

        // ---------------- Phase B: s += adj[rows,:] @ q_t  (waves split K) ----------------
        {
            f32x4 acc[4];
#pragma unroll
            for (int nt = 0; nt < 4; ++nt) acc[nt] = (f32x4){0.f, 0.f, 0.f, 0.f};
            const int koff = wave * 512 + quad * 8;
            const unsigned short* qp0 = qcur + (0 * 16 + l15) * N_NODES + koff;
            const unsigned short* qp1 = qcur + (1 * 16 + l15) * N_NODES + koff;
            const unsigned short* qp2 = qcur + (2 * 16 + l15) * N_NODES + koff;
            const unsigned short* qp3 = qcur + (3 * 16 + l15) * N_NODES + koff;
            const float* ap = adjlane;
#pragma unroll 4
            for (int kk = 0; kk < 16; ++kk) {
                short8 a;
                if (ADJL) a = *(const short8*)(albase + kk * 32);
                else      a = cvt8_trunc(ap + kk * 32);
                short8 b0 = *(const short8*)(qp0 + kk * 32);
                short8 b1 = *(const short8*)(qp1 + kk * 32);
                short8 b2 = *(const short8*)(qp2 + kk * 32);
                short8 b3 = *(const short8*)(qp3 + kk * 32);
                acc[0] = MFMA16(a, b0, acc[0]);
                acc[1] = MFMA16(a, b1, acc[1]);
                acc[2] = MFMA16(a, b2, acc[2]);
                acc[3] = MFMA16(a, b3, acc[3]);
            }
#pragma unroll
            for (int nt = 0; nt < 4; ++nt)
#pragma unroll
                for (int r = 0; r < 4; ++r)
                    atomicAdd(&s_lds[(quad * 4 + r) * 66 + nt * 16 + l15], acc[nt][r]);
        }
        __syncthreads();

        // ---------------- Phase C: state update + h output (fp32), reset s ----------------
        {
            const int r  = tid >> 5;
            const int c0 = (tid & 31) * 2;
            float hn[2];
#pragma unroll
            for (int j = 0; j < 2; ++j) {
                int cc = c0 + j;
                float s = s_lds[r * 66 + cc];
                s_lds[r * 66 + cc] = 0.f;                 // ready for next step
                float iv = gate_lds[(0 * 16 + r) * 64 + cc];
                float fv = gate_lds[(1 * 16 + r) * 64 + cc];
                float gv = gate_lds[(2 * 16 + r) * 64 + cc];
                float ov = gate_lds[(3 * 16 + r) * 64 + cc];
                float cn = fv * (c_lds[r * 64 + cc] + s) + iv * gv;
                hn[j] = ov * fast_tanh(cn);
                c_lds[r * 64 + cc] = cn;
            }
            us2 hv; hv[0] = f2bf(hn[0]); hv[1] = f2bf(hn[1]);
            *(us2*)(h_lds + r * 72 + c0) = hv;
            *(f32x2*)(out + ((size_t)(rowbase + r) * T_STEPS + t) * H_DIM + c0) = (f32x2){hn[0], hn[1]};
        }
        __syncthreads();

        // ---------------- Phase D: q_{t+1} = tanh(h @ Wq + bq), stored transposed ----------------
        if (t < T_STEPS - 1 && wave < 4) {
            f32x4 acc = {0.f, 0.f, 0.f, 0.f};
#pragma unroll
            for (int kk = 0; kk < 2; ++kk) {
                short8 a = *(const short8*)(h_lds + l15 * 72 + kk * 32 + quad * 8);
                acc = MFMA16(a, wQ[kk], acc);
            }
            us4 qv;
#pragma unroll
            for (int r = 0; r < 4; ++r) qv[r] = f2bf(fast_tanh(acc[r] + bqv));
            *(us4*)(qnxt + hhq * N_NODES + rowbase + quad * 4) = qv;
        }

        if (t < T_STEPS - 1) {
            xa = *(const f32x4*)(xlane + (t + 1) * 32);       // prefetch x across barrier
            xb = *(const f32x4*)(xlane + (t + 1) * 32 + 4);
            grid_barrier(flags, bid, tid, t + 2);
        }
    }
}

extern "C" void kernel_launch(void* const* d_in, const int* in_sizes, int n_in,
                              void* d_out, int out_size, void* d_ws, size_t ws_size,
                              hipStream_t stream) {
    if (ws_size < WS_NEED) return;
    const float* x      = (const float*)d_in[0];
    const float* adj    = (const float*)d_in[1];
    const float* w_ih   = (const float*)d_in[2];
    const float* w_hh   = (const float*)d_in[3];
    const float* bias   = (const float*)d_in[4];
    const float* w_q    = (const float*)d_in[5];
    const float* bias_q = (const float*)d_in[6];
    float* o = (float*)d_out;
    unsigned char* w = (unsigned char*)d_ws;

    hipError_t e = hipFuncSetAttribute((const void*)glstm_kernel<true>,
                                       hipFuncAttributeMaxDynamicSharedMemorySize, SMEM_BIG);
    if (e == hipSuccess) {
        glstm_kernel<true><<<NBLK, NTHR, SMEM_BIG, stream>>>(x, adj, w_ih, w_hh, bias, w_q, bias_q, o, w);
    } else {
        glstm_kernel<false><<<NBLK, NTHR, SMEM_SMALL, stream>>>(x, adj, w_ih, w_hh, bias, w_q, bias_q, o, w);
    }
}